// Round 1
// baseline (85.090 us; speedup 1.0000x reference)
//
#include <hip/hip_runtime.h>

// ShortConvolution: depthwise causal conv (W=4, 3-tap history from cache) + SiLU + residual.
// out[b,t,d] = silu( sum_{w=0..3} win[t-3+w] * weight[d,w] ) + residual[b,t,d]
//   where win[j] = x[b,j,d] for j>=0, cache[b,d,j+4] for j in [-3,-1]  (cache[...,0] unused).

constexpr int B = 4, T = 4096, D = 2048, W = 4;
constexpr int THREADS = 256;
constexpr int TCHUNK = 32;            // t-steps per thread; 3/32 ~ 9% x re-read overhead
constexpr int D4 = D / 4;             // 512 float4 columns

__global__ __launch_bounds__(THREADS)
void shortconv_silu_res_kernel(const float4* __restrict__ x,         // (B,T,D4)
                               const float4* __restrict__ residual,  // (B,T,D4)
                               const float*  __restrict__ cache,     // (B,D,W)
                               const float4* __restrict__ weight,    // (D) float4 = 4 taps
                               float4*       __restrict__ out)       // (B,T,D4)
{
    const int c4 = blockIdx.x * THREADS + threadIdx.x;   // which float4 column (0..D4-1)
    const int t0 = blockIdx.y * TCHUNK;
    const int b  = blockIdx.z;
    const int d0 = c4 * 4;

    // Per-channel taps: wv[i] = (w0,w1,w2,w3) for channel d0+i. 16B-aligned (d0*W*4B).
    const float4 wv0 = weight[d0 + 0];
    const float4 wv1 = weight[d0 + 1];
    const float4 wv2 = weight[d0 + 2];
    const float4 wv3 = weight[d0 + 3];

    const size_t xbase = (size_t)b * T * D4 + c4;

    // Sliding window: xm3 = win[t-3], xm2 = win[t-2], xm1 = win[t-1] (each across 4 channels)
    float4 xm3, xm2, xm1;
    if (t0 == 0) {
        // cache[b, d0+i, w]; 4 channels x 4 taps are 16 contiguous floats
        const float4* cv = (const float4*)(cache + ((size_t)b * D + d0) * W);
        const float4 c0 = cv[0], c1 = cv[1], c2 = cv[2], c3 = cv[3];
        xm3 = make_float4(c0.y, c1.y, c2.y, c3.y);   // cache[...,1]
        xm2 = make_float4(c0.z, c1.z, c2.z, c3.z);   // cache[...,2]
        xm1 = make_float4(c0.w, c1.w, c2.w, c3.w);   // cache[...,3]
    } else {
        xm3 = x[xbase + (size_t)(t0 - 3) * D4];
        xm2 = x[xbase + (size_t)(t0 - 2) * D4];
        xm1 = x[xbase + (size_t)(t0 - 1) * D4];
    }

    #pragma unroll 4
    for (int t = t0; t < t0 + TCHUNK; ++t) {
        const size_t idx = xbase + (size_t)t * D4;
        const float4 xc = x[idx];
        const float4 r  = residual[idx];
        float4 o;
        float z;
        z   = xm3.x * wv0.x + xm2.x * wv0.y + xm1.x * wv0.z + xc.x * wv0.w;
        o.x = __fdividef(z, 1.f + __expf(-z)) + r.x;
        z   = xm3.y * wv1.x + xm2.y * wv1.y + xm1.y * wv1.z + xc.y * wv1.w;
        o.y = __fdividef(z, 1.f + __expf(-z)) + r.y;
        z   = xm3.z * wv2.x + xm2.z * wv2.y + xm1.z * wv2.z + xc.z * wv2.w;
        o.z = __fdividef(z, 1.f + __expf(-z)) + r.z;
        z   = xm3.w * wv3.x + xm2.w * wv3.y + xm1.w * wv3.z + xc.w * wv3.w;
        o.w = __fdividef(z, 1.f + __expf(-z)) + r.w;
        out[idx] = o;
        xm3 = xm2; xm2 = xm1; xm1 = xc;
    }
}

extern "C" void kernel_launch(void* const* d_in, const int* in_sizes, int n_in,
                              void* d_out, int out_size, void* d_ws, size_t ws_size,
                              hipStream_t stream) {
    const float4* x        = (const float4*)d_in[0];
    const float4* residual = (const float4*)d_in[1];
    const float*  cache    = (const float*)d_in[2];
    const float4* weight   = (const float4*)d_in[3];
    float4* out = (float4*)d_out;

    dim3 grid(D4 / THREADS, T / TCHUNK, B);   // 2 x 128 x 4 = 1024 blocks
    shortconv_silu_res_kernel<<<grid, dim3(THREADS), 0, stream>>>(x, residual, cache, weight, out);
}

// Round 3
// 71.113 us; speedup vs baseline: 1.1965x; 1.1965x over previous
//
#include <hip/hip_runtime.h>

// ShortConvolution: depthwise causal conv (W=4, 3-tap history from cache) + SiLU + residual.
// out[b,t,d] = silu( sum_{w=0..3} win[t-3+w] * weight[d,w] ) + residual[b,t,d]
//   where win[j] = x[b,j,d] for j>=0, cache[b,d,j+4] for j in [-3,-1]  (cache[...,0] unused).

constexpr int B = 4, T = 4096, D = 2048, W = 4;
constexpr int THREADS = 256;
constexpr int TCHUNK = 16;            // t-steps per thread; 2048 blocks -> 32 waves/CU (full occupancy)
constexpr int D4 = D / 4;             // 512 float4 columns

typedef float floatx4 __attribute__((ext_vector_type(4)));  // native vec type for nontemporal builtin

__global__ __launch_bounds__(THREADS)
void shortconv_silu_res_kernel(const float4* __restrict__ x,         // (B,T,D4)
                               const float4* __restrict__ residual,  // (B,T,D4)
                               const float*  __restrict__ cache,     // (B,D,W)
                               const float4* __restrict__ weight,    // (D) float4 = 4 taps
                               float4*       __restrict__ out)       // (B,T,D4)
{
    const int c4 = blockIdx.x * THREADS + threadIdx.x;   // which float4 column (0..D4-1)
    const int t0 = blockIdx.y * TCHUNK;
    const int b  = blockIdx.z;
    const int d0 = c4 * 4;

    // Per-channel taps: wv[i] = (w0,w1,w2,w3) for channel d0+i. 16B-aligned (d0*W*4B).
    const float4 wv0 = weight[d0 + 0];
    const float4 wv1 = weight[d0 + 1];
    const float4 wv2 = weight[d0 + 2];
    const float4 wv3 = weight[d0 + 3];

    const size_t xbase = (size_t)b * T * D4 + c4;

    // Sliding window: xm3 = win[t-3], xm2 = win[t-2], xm1 = win[t-1] (each across 4 channels)
    float4 xm3, xm2, xm1;
    if (t0 == 0) {
        // cache[b, d0+i, w]; 4 channels x 4 taps are 16 contiguous floats
        const float4* cv = (const float4*)(cache + ((size_t)b * D + d0) * W);
        const float4 c0 = cv[0], c1 = cv[1], c2 = cv[2], c3 = cv[3];
        xm3 = make_float4(c0.y, c1.y, c2.y, c3.y);   // cache[...,1]
        xm2 = make_float4(c0.z, c1.z, c2.z, c3.z);   // cache[...,2]
        xm1 = make_float4(c0.w, c1.w, c2.w, c3.w);   // cache[...,3]
    } else {
        xm3 = x[xbase + (size_t)(t0 - 3) * D4];
        xm2 = x[xbase + (size_t)(t0 - 2) * D4];
        xm1 = x[xbase + (size_t)(t0 - 1) * D4];
    }

    #pragma unroll 4
    for (int t = t0; t < t0 + TCHUNK; ++t) {
        const size_t idx = xbase + (size_t)t * D4;
        const float4 xc = x[idx];
        const float4 r  = residual[idx];
        floatx4 o;
        float z;
        z   = xm3.x * wv0.x + xm2.x * wv0.y + xm1.x * wv0.z + xc.x * wv0.w;
        o.x = __fdividef(z, 1.f + __expf(-z)) + r.x;
        z   = xm3.y * wv1.x + xm2.y * wv1.y + xm1.y * wv1.z + xc.y * wv1.w;
        o.y = __fdividef(z, 1.f + __expf(-z)) + r.y;
        z   = xm3.z * wv2.x + xm2.z * wv2.y + xm1.z * wv2.z + xc.z * wv2.w;
        o.z = __fdividef(z, 1.f + __expf(-z)) + r.z;
        z   = xm3.w * wv3.x + xm2.w * wv3.y + xm1.w * wv3.z + xc.w * wv3.w;
        o.w = __fdividef(z, 1.f + __expf(-z)) + r.w;
        // streaming store: keep L2/L3 capacity for x boundary reuse
        __builtin_nontemporal_store(o, (floatx4*)&out[idx]);
        xm3 = xm2; xm2 = xm1; xm1 = xc;
    }
}

extern "C" void kernel_launch(void* const* d_in, const int* in_sizes, int n_in,
                              void* d_out, int out_size, void* d_ws, size_t ws_size,
                              hipStream_t stream) {
    const float4* x        = (const float4*)d_in[0];
    const float4* residual = (const float4*)d_in[1];
    const float*  cache    = (const float*)d_in[2];
    const float4* weight   = (const float4*)d_in[3];
    float4* out = (float4*)d_out;

    dim3 grid(D4 / THREADS, T / TCHUNK, B);   // 2 x 256 x 4 = 2048 blocks
    shortconv_silu_res_kernel<<<grid, dim3(THREADS), 0, stream>>>(x, residual, cache, weight, out);
}